// Round 12
// baseline (1646.903 us; speedup 1.0000x reference)
//
#include <hip/hip_runtime.h>
#include <hip/hip_bf16.h>

typedef short short8 __attribute__((ext_vector_type(8)));
typedef float f32x4 __attribute__((ext_vector_type(4)));
typedef unsigned long long u64;
typedef unsigned u32;

constexpr int S = 256, B = 64, IN = 512, H = 1024;
constexpr int M = S * B;        // 16384
constexpr int NG = 4 * H;       // 4096

// ---------------- prep ----------------
__global__ void f2b(const float* __restrict__ s, __hip_bfloat16* __restrict__ d, int n4) {
  int i = blockIdx.x * blockDim.x + threadIdx.x;
  if (i >= n4) return;
  float4 v = reinterpret_cast<const float4*>(s)[i];
  __hip_bfloat16 o[4] = {__float2bfloat16(v.x), __float2bfloat16(v.y),
                         __float2bfloat16(v.z), __float2bfloat16(v.w)};
  *reinterpret_cast<uint2*>(d + 4 * (size_t)i) = *reinterpret_cast<uint2*>(o);
}

// all 8 weight matrices in one launch: Wx 4x(H*IN) then Wh 4x(H*H), float4 units
__global__ void wconv(const float* w0, const float* w1, const float* w2, const float* w3,
                      const float* w4, const float* w5, const float* w6, const float* w7,
                      __hip_bfloat16* __restrict__ wxb, __hip_bfloat16* __restrict__ whb) {
  const int QX = H * IN / 4;
  const int QH = H * H / 4;
  int i = blockIdx.x * blockDim.x + threadIdx.x;
  const float* src;
  __hip_bfloat16* dst;
  int off;
  if (i < 4 * QX) {
    int g = i / QX; off = i - g * QX;
    src = g == 0 ? w0 : g == 1 ? w1 : g == 2 ? w2 : w3;
    dst = wxb + (size_t)g * H * IN;
  } else {
    int k = i - 4 * QX;
    if (k >= 4 * QH) return;
    int g = k / QH; off = k - g * QH;
    src = g == 0 ? w4 : g == 1 ? w5 : g == 2 ? w6 : w7;
    dst = whb + (size_t)g * H * H;
  }
  float4 v = reinterpret_cast<const float4*>(src)[off];
  __hip_bfloat16 o[4] = {__float2bfloat16(v.x), __float2bfloat16(v.y),
                         __float2bfloat16(v.z), __float2bfloat16(v.w)};
  *reinterpret_cast<uint2*>(dst + 4 * (size_t)off) = *reinterpret_cast<uint2*>(o);
}

__global__ void bias_k(const float* bx0, const float* bx1, const float* bx2, const float* bx3,
                       const float* bh0, const float* bh1, const float* bh2, const float* bh3,
                       float* bias) {
  int i = blockIdx.x * blockDim.x + threadIdx.x;
  if (i >= NG) return;
  int g = i >> 10, j = i & 1023;
  const float* bx = g == 0 ? bx0 : g == 1 ? bx1 : g == 2 ? bx2 : bx3;
  const float* bh = g == 0 ? bh0 : g == 1 ? bh1 : g == 2 ? bh2 : bh3;
  bias[i] = bx[j] + bh[j];
}

__device__ __forceinline__ u64 ldq(const u64* p) {
  return __hip_atomic_load(p, __ATOMIC_RELAXED, __HIP_MEMORY_SCOPE_AGENT);
}
__device__ __forceinline__ u32 ldw(const u32* p) {
  return __hip_atomic_load(p, __ATOMIC_RELAXED, __HIP_MEMORY_SCOPE_AGENT);
}
__device__ __forceinline__ void stw(u32* p, u32 v) {
  __hip_atomic_store(p, v, __ATOMIC_RELAXED, __HIP_MEMORY_SCOPE_AGENT);
}
__device__ __forceinline__ void stq(u64* p, u64 v) {
  __hip_atomic_store(p, v, __ATOMIC_RELAXED, __HIP_MEMORY_SCOPE_AGENT);
}
__device__ __forceinline__ float sigm(float x) {
  return __builtin_amdgcn_rcpf(1.f + __expf(-x));
}
__device__ __forceinline__ float tanhfast(float x) {
  return 2.f * __builtin_amdgcn_rcpf(1.f + __expf(-2.f * x)) - 1.f;
}
// block barrier that only drains LDS (no vmcnt -> no store-ack RTT)
__device__ __forceinline__ void bar_lds() {
  asm volatile("s_waitcnt lgkmcnt(0)" ::: "memory");
  __builtin_amdgcn_sched_barrier(0);
  __builtin_amdgcn_s_barrier();
  __builtin_amdgcn_sched_barrier(0);
}

// ---------------- fused persistent LSTM: gx K-split, small live window ----------------
// 256 blocks (bg<<6|jg) x 4 waves, 1 block/CU (LDS-forced). Wave w per step:
//   gx partial: K in [w*128,+128) of IN=512, all 4 gates (xa[4]+wb[16] = 80 VGPR,
//               loaded AFTER poll-detect, BEFORE h loads -> gx MFMA waits only
//               vmcnt(16) [gx loads older] and runs inside the h-load RTT window)
//   gh partial: K in [w*256,+256) of H=1024, all 4 gates (h = A-frags direct)
// Both accumulate into acc[g] (identical C-layout); cross-wave gt reduction sums.
// Protocol per step (r10 winner): h stores (sc1) -> vmcnt(0) -> s_barrier ->
// one monotone flag/block; consumer polls 16 flags then loads h exactly once.
__global__ __launch_bounds__(256, 1) void lstm_rec(const __hip_bfloat16* __restrict__ whb,
                                                   const __hip_bfloat16* __restrict__ xb,
                                                   const __hip_bfloat16* __restrict__ wxb,
                                                   const float* __restrict__ bias,
                                                   __hip_bfloat16* __restrict__ hx,
                                                   u32* __restrict__ flags,
                                                   float* __restrict__ out) {
  __shared__ __align__(16) ushort Bf[4][32][64][8];   // 128 KB: Wh slice, B-frag order
  __shared__ __align__(16) float gt[4][4][16][20];    // 20 KB
  const int tid = threadIdx.x;
  const int l = tid & 63, w = tid >> 6;
  const int jg = blockIdx.x & 63, bg = blockIdx.x >> 6;
  const int j0 = jg * 16, b0 = bg * 16;

  // stage Wh slice into LDS, pre-swizzled to MFMA B-fragment order (once)
  for (int idx = tid; idx < 4 * 32 * 64; idx += 256) {
    int g = idx >> 11, kb = (idx >> 6) & 31, ll = idx & 63;
    const __hip_bfloat16* src =
        whb + ((size_t)(g * H + j0 + (ll & 15))) * H + kb * 32 + (ll >> 4) * 8;
    *reinterpret_cast<uint4*>(&Bf[g][kb][ll][0]) = *reinterpret_cast<const uint4*>(src);
  }
  __syncthreads();

  const int cr = l & 15, kg = l >> 4;
  const int bi = tid >> 4, j = tid & 15;
  const u32* myfl = flags + (size_t)((bg << 6) + w * 16 + (l & 15)) * 16;
  u32* pubfl = flags + (size_t)((bg << 6) + jg) * 16;

  // step-invariant: bias (4 gates at this thread's j) and gx operand bases
  float bias4[4];
#pragma unroll
  for (int g = 0; g < 4; ++g) bias4[g] = bias[(g << 10) + j0 + j];
  const __hip_bfloat16* wxr0 = wxb + ((size_t)(0 * H) + j0 + cr) * IN + w * 128 + kg * 8;
  const __hip_bfloat16* wxr1 = wxb + ((size_t)(1 * H) + j0 + cr) * IN + w * 128 + kg * 8;
  const __hip_bfloat16* wxr2 = wxb + ((size_t)(2 * H) + j0 + cr) * IN + w * 128 + kg * 8;
  const __hip_bfloat16* wxr3 = wxb + ((size_t)(3 * H) + j0 + cr) * IN + w * 128 + kg * 8;

  float c = 0.f;

  for (int t = 0; t < S; ++t) {
    const __hip_bfloat16* hsrc = hx + (size_t)(t & 1) * (B * H);
    __hip_bfloat16* hdst = hx + (size_t)((t + 1) & 1) * (B * H);

    if (t > 0) {
      // flag wait: one word/lane over this wave's 16 producer blocks (clean poll,
      // no other VMEM outstanding)
      while (!__all(ldw(myfl) >= (u32)t)) ;
      asm volatile("" ::: "memory");
    }

    // ---- gx operand loads FIRST (older in vmcnt order; L2-resident Wx) ----
    const __hip_bfloat16* xr = xb + ((size_t)(t * B) + b0 + cr) * IN + w * 128 + kg * 8;
    short8 xa[4], wb[4][4];
#pragma unroll
    for (int kb = 0; kb < 4; ++kb) {
      xa[kb] = *reinterpret_cast<const short8*>(xr + kb * 32);
      wb[0][kb] = *reinterpret_cast<const short8*>(wxr0 + kb * 32);
      wb[1][kb] = *reinterpret_cast<const short8*>(wxr1 + kb * 32);
      wb[2][kb] = *reinterpret_cast<const short8*>(wxr2 + kb * 32);
      wb[3][kb] = *reinterpret_cast<const short8*>(wxr3 + kb * 32);
    }
    __builtin_amdgcn_sched_barrier(0);   // keep gx loads older than h loads

    // ---- h loads (newest; sc1 via L3; these ARE the gh A-fragments) ----
    union { u64 q[2]; short8 s; } ua[8];
    if (t > 0) {
      const u64* hp =
          reinterpret_cast<const u64*>(hsrc + (size_t)(b0 + cr) * H + w * 256 + kg * 8);
#pragma unroll
      for (int kk = 0; kk < 8; ++kk) {
        ua[kk].q[0] = ldq(hp + kk * 8);
        ua[kk].q[1] = ldq(hp + kk * 8 + 1);
      }
    } else {
#pragma unroll
      for (int kk = 0; kk < 8; ++kk) { ua[kk].q[0] = 0; ua[kk].q[1] = 0; }
    }

    // ---- gx MFMA (waits vmcnt(16): gx loads done, h still in flight) ----
    f32x4 acc[4] = {};
#pragma unroll
    for (int kb = 0; kb < 4; ++kb) {
#pragma unroll
      for (int g = 0; g < 4; ++g)
        acc[g] = __builtin_amdgcn_mfma_f32_16x16x32_bf16(xa[kb], wb[g][kb], acc[g], 0, 0, 0);
    }

    // ---- gh MFMA over this wave's K range (B-frags from LDS) ----
#pragma unroll
    for (int kk = 0; kk < 8; ++kk) {
#pragma unroll
      for (int g = 0; g < 4; ++g) {
        short8 bv = *reinterpret_cast<const short8*>(&Bf[g][w * 8 + kk][l][0]);
        acc[g] = __builtin_amdgcn_mfma_f32_16x16x32_bf16(ua[kk].s, bv, acc[g], 0, 0, 0);
      }
    }
#pragma unroll
    for (int g = 0; g < 4; ++g)
      *reinterpret_cast<f32x4*>(&gt[w][g][cr][kg * 4]) = acc[g];
    bar_lds();   // gt writes visible (lgkm only)

    // cross-wave reduction + gates (thread owns (batch=bi, hidden=j))
    float sf = 0.f, si = 0.f, so = 0.f, sc = 0.f;
#pragma unroll
    for (int wv = 0; wv < 4; ++wv) {
      sf += gt[wv][0][j][bi];
      si += gt[wv][1][j][bi];
      so += gt[wv][2][j][bi];
      sc += gt[wv][3][j][bi];
    }
    float gf = sf + bias4[0];
    float gi = si + bias4[1];
    float go = so + bias4[2];
    float gc = sc + bias4[3];
    float f = sigm(gf);
    float i_ = sigm(gi);
    float o = sigm(go);
    float cn = f * c + i_ * tanhfast(gc);
    float hn = o * tanhfast(cn);
    c = cn;

    // ---- publish path FIRST: pack bf16 h (2 shfl), store, drain, flag ----
    u32 hs16 = (u32)__bfloat16_as_ushort(__float2bfloat16(hn));
    u32 p1 = (hs16 & 0xffffu) | ((u32)__shfl_xor((int)hs16, 1) << 16);
    u32 p2 = (u32)__shfl_xor((int)p1, 2);
    if (t < S - 1) {
      if ((j & 3) == 0) {
        u64 pk = (u64)p1 | ((u64)p2 << 32);
        stq(reinterpret_cast<u64*>(hdst + (size_t)(b0 + bi) * H + j0 + j), pk);
      }
      // drain h stores (L3 ack), join waves, publish one flag.
      // This s_barrier also serves as the gt WAR barrier for the next step.
      asm volatile("s_waitcnt vmcnt(0)" ::: "memory");
      __builtin_amdgcn_sched_barrier(0);
      __builtin_amdgcn_s_barrier();
      __builtin_amdgcn_sched_barrier(0);
      if (tid == 0) stw(pubfl, (u32)(t + 1));
    }

    // ---- off-path stores: pack 4 lanes -> one float4 (acks overlap next wait) ----
    {
      u32 f0 = __float_as_uint(hn);
      u64 a = (u64)f0 | ((u64)(u32)__shfl_xor((int)f0, 1) << 32);
      u64 b = (u64)__shfl_xor((long long)a, 2);
      if ((j & 3) == 0) {
        uint4 v = make_uint4((u32)a, (u32)(a >> 32), (u32)b, (u32)(b >> 32));
        *reinterpret_cast<uint4*>(&out[((size_t)(t * B + b0 + bi)) * H + j0 + j]) = v;
      }
    }
    if (t == S - 1) {
      out[(size_t)S * B * H + (size_t)(b0 + bi) * H + j0 + j] = hn;
      out[(size_t)S * B * H + (size_t)B * H + (size_t)(b0 + bi) * H + j0 + j] = cn;
    }
  }
}

extern "C" void kernel_launch(void* const* d_in, const int* in_sizes, int n_in,
                              void* d_out, int out_size, void* d_ws, size_t ws_size,
                              hipStream_t stream) {
  const float* x = (const float*)d_in[0];
  const float* Wx[4] = {(const float*)d_in[1], (const float*)d_in[3],
                        (const float*)d_in[5], (const float*)d_in[7]};
  const float* bx[4] = {(const float*)d_in[2], (const float*)d_in[4],
                        (const float*)d_in[6], (const float*)d_in[8]};
  const float* Wh[4] = {(const float*)d_in[9], (const float*)d_in[11],
                        (const float*)d_in[13], (const float*)d_in[15]};
  const float* bh[4] = {(const float*)d_in[10], (const float*)d_in[12],
                        (const float*)d_in[14], (const float*)d_in[16]};

  char* ws = (char*)d_ws;
  size_t o_flags = 0;                                 // 256 slots x 64B = 16 KB
  size_t o_hx = 16384;
  size_t o_bias = o_hx + (size_t)2 * B * H * 2;       // hx ping-pong bf16: 256 KB
  size_t o_x = o_bias + (size_t)NG * 4;
  size_t o_wx = o_x + (size_t)M * IN * 2;             // xb: 16 MB
  size_t o_wh = o_wx + (size_t)NG * IN * 2;           // wxb: 4 MB
  // whb: 8 MB

  u32* flagsp = (u32*)(ws + o_flags);
  __hip_bfloat16* hxp = (__hip_bfloat16*)(ws + o_hx);
  float* biasp = (float*)(ws + o_bias);
  __hip_bfloat16* xb = (__hip_bfloat16*)(ws + o_x);
  __hip_bfloat16* wxb = (__hip_bfloat16*)(ws + o_wx);
  __hip_bfloat16* whb = (__hip_bfloat16*)(ws + o_wh);

  // zero only the 16 KB flag array each launch (monotone counters)
  hipMemsetAsync(ws, 0, 16384, stream);

  f2b<<<(M * IN / 4) / 256, 256, 0, stream>>>(x, xb, M * IN / 4);
  {
    int total4 = 4 * (H * IN / 4) + 4 * (H * H / 4);
    wconv<<<(total4 + 255) / 256, 256, 0, stream>>>(
        Wx[0], Wx[1], Wx[2], Wx[3], Wh[0], Wh[1], Wh[2], Wh[3], wxb, whb);
  }
  bias_k<<<NG / 256, 256, 0, stream>>>(bx[0], bx[1], bx[2], bx[3],
                                       bh[0], bh[1], bh[2], bh[3], biasp);

  lstm_rec<<<256, 256, 0, stream>>>(whb, xb, wxb, biasp, hxp, flagsp, (float*)d_out);
}

// Round 13
// 1193.986 us; speedup vs baseline: 1.3793x; 1.3793x over previous
//
#include <hip/hip_runtime.h>
#include <hip/hip_bf16.h>

typedef short short8 __attribute__((ext_vector_type(8)));
typedef float f32x4 __attribute__((ext_vector_type(4)));
typedef unsigned long long u64;
typedef unsigned u32;

constexpr int S = 256, B = 64, IN = 512, H = 1024;
constexpr int M = S * B;        // 16384
constexpr int NG = 4 * H;       // 4096

// ---------------- prep ----------------
__global__ void f2b(const float* __restrict__ s, __hip_bfloat16* __restrict__ d, int n4) {
  int i = blockIdx.x * blockDim.x + threadIdx.x;
  if (i >= n4) return;
  float4 v = reinterpret_cast<const float4*>(s)[i];
  __hip_bfloat16 o[4] = {__float2bfloat16(v.x), __float2bfloat16(v.y),
                         __float2bfloat16(v.z), __float2bfloat16(v.w)};
  *reinterpret_cast<uint2*>(d + 4 * (size_t)i) = *reinterpret_cast<uint2*>(o);
}

// all 8 weight matrices in one launch: Wx 4x(H*IN) then Wh 4x(H*H), float4 units
__global__ void wconv(const float* w0, const float* w1, const float* w2, const float* w3,
                      const float* w4, const float* w5, const float* w6, const float* w7,
                      __hip_bfloat16* __restrict__ wxb, __hip_bfloat16* __restrict__ whb) {
  const int QX = H * IN / 4;
  const int QH = H * H / 4;
  int i = blockIdx.x * blockDim.x + threadIdx.x;
  const float* src;
  __hip_bfloat16* dst;
  int off;
  if (i < 4 * QX) {
    int g = i / QX; off = i - g * QX;
    src = g == 0 ? w0 : g == 1 ? w1 : g == 2 ? w2 : w3;
    dst = wxb + (size_t)g * H * IN;
  } else {
    int k = i - 4 * QX;
    if (k >= 4 * QH) return;
    int g = k / QH; off = k - g * QH;
    src = g == 0 ? w4 : g == 1 ? w5 : g == 2 ? w6 : w7;
    dst = whb + (size_t)g * H * H;
  }
  float4 v = reinterpret_cast<const float4*>(src)[off];
  __hip_bfloat16 o[4] = {__float2bfloat16(v.x), __float2bfloat16(v.y),
                         __float2bfloat16(v.z), __float2bfloat16(v.w)};
  *reinterpret_cast<uint2*>(dst + 4 * (size_t)off) = *reinterpret_cast<uint2*>(o);
}

__global__ void bias_k(const float* bx0, const float* bx1, const float* bx2, const float* bx3,
                       const float* bh0, const float* bh1, const float* bh2, const float* bh3,
                       float* bias) {
  int i = blockIdx.x * blockDim.x + threadIdx.x;
  if (i >= NG) return;
  int g = i >> 10, j = i & 1023;
  const float* bx = g == 0 ? bx0 : g == 1 ? bx1 : g == 2 ? bx2 : bx3;
  const float* bh = g == 0 ? bh0 : g == 1 ? bh1 : g == 2 ? bh2 : bh3;
  bias[i] = bx[j] + bh[j];
}

// ---------------- gx = x @ Wx^T + bias : m97-structure, output [m][j][gate] ----------------
__global__ __launch_bounds__(256) void gx_gemm(const __hip_bfloat16* __restrict__ xb,
                                               const __hip_bfloat16* __restrict__ wxb,
                                               const float* __restrict__ bias,
                                               __hip_bfloat16* __restrict__ gx) {
  __shared__ __align__(16) ushort As[4][128][8];   // 8 KB
  __shared__ __align__(16) ushort Bs[4][128][8];   // 8 KB
  const int tid = threadIdx.x;
  const int l = tid & 63, w = tid >> 6;
  const int m0 = blockIdx.y * 128, n0 = blockIdx.x * 128;
  const int wm = (w >> 1) * 64, wn = (w & 1) * 64;
  const int cr = l & 15, kg = l >> 4;
  f32x4 acc[4][4] = {};

  ushort* Af = &As[0][0][0];
  ushort* Bfl = &Bs[0][0][0];

  for (int k0 = 0; k0 < IN; k0 += 32) {
    __syncthreads();
#pragma unroll
    for (int n = 0; n < 2; ++n) {
      int cA = w * 2 + n;            // chunk 0..7 (1 KB each)
      int f = cA * 64 + l;           // flat 16B-unit index: seg=f>>7, row=f&127
      const __hip_bfloat16* ga = xb + (size_t)(m0 + (f & 127)) * IN + k0 + (f >> 7) * 8;
      const __hip_bfloat16* gb = wxb + (size_t)(n0 + (f & 127)) * IN + k0 + (f >> 7) * 8;
      __builtin_amdgcn_global_load_lds((const u32*)ga, (u32*)(Af + cA * 512), 16, 0, 0);
      __builtin_amdgcn_global_load_lds((const u32*)gb, (u32*)(Bfl + cA * 512), 16, 0, 0);
    }
    __syncthreads();
    short8 a[4], b[4];
#pragma unroll
    for (int mi = 0; mi < 4; ++mi)
      a[mi] = *reinterpret_cast<const short8*>(&As[kg][wm + mi * 16 + cr][0]);
#pragma unroll
    for (int ni = 0; ni < 4; ++ni)
      b[ni] = *reinterpret_cast<const short8*>(&Bs[kg][wn + ni * 16 + cr][0]);
#pragma unroll
    for (int mi = 0; mi < 4; ++mi)
#pragma unroll
      for (int ni = 0; ni < 4; ++ni)
        acc[mi][ni] = __builtin_amdgcn_mfma_f32_16x16x32_bf16(a[mi], b[ni], acc[mi][ni], 0, 0, 0);
  }

#pragma unroll
  for (int ni = 0; ni < 4; ++ni) {
    int n = n0 + wn + ni * 16 + cr;
    float bv = bias[n];
    int g = n >> 10, j = n & 1023;
#pragma unroll
    for (int mi = 0; mi < 4; ++mi) {
#pragma unroll
      for (int r = 0; r < 4; ++r) {
        int m = m0 + wm + mi * 16 + kg * 4 + r;
        gx[((size_t)m * H + j) * 4 + g] = __float2bfloat16(acc[mi][ni][r] + bv);
      }
    }
  }
}

__device__ __forceinline__ u64 ldq(const u64* p) {
  return __hip_atomic_load(p, __ATOMIC_RELAXED, __HIP_MEMORY_SCOPE_AGENT);
}
__device__ __forceinline__ u32 ldw(const u32* p) {
  return __hip_atomic_load(p, __ATOMIC_RELAXED, __HIP_MEMORY_SCOPE_AGENT);
}
__device__ __forceinline__ void stw(u32* p, u32 v) {
  __hip_atomic_store(p, v, __ATOMIC_RELAXED, __HIP_MEMORY_SCOPE_AGENT);
}
__device__ __forceinline__ void stq(u64* p, u64 v) {
  __hip_atomic_store(p, v, __ATOMIC_RELAXED, __HIP_MEMORY_SCOPE_AGENT);
}
__device__ __forceinline__ float sigm(float x) {
  return __builtin_amdgcn_rcpf(1.f + __expf(-x));
}
__device__ __forceinline__ float tanhfast(float x) {
  return 2.f * __builtin_amdgcn_rcpf(1.f + __expf(-2.f * x)) - 1.f;
}
// block barrier that only drains LDS (no vmcnt -> no store-ack RTT)
__device__ __forceinline__ void bar_lds() {
  asm volatile("s_waitcnt lgkmcnt(0)" ::: "memory");
  __builtin_amdgcn_sched_barrier(0);
  __builtin_amdgcn_s_barrier();
  __builtin_amdgcn_sched_barrier(0);
}

// ---------------- persistent recurrence: drain -> per-block flag -> load-once ----------------
// r10 protocol (winner), plus: (1) gq prefetched one step ahead right after the
// h loads (register double-buffer) and (2) out stores buffered in an 8-step LDS
// ring flushed just before the h-publish of steps t%8==7, so the drain absorbs
// their acks. Net effect: NOTHING is outstanding in vmcnt when the poll starts,
// so the first poll iteration waits only the flag-load RTT.
__global__ __launch_bounds__(256, 1) void lstm_rec(const __hip_bfloat16* __restrict__ whb,
                                                   const __hip_bfloat16* __restrict__ gx,
                                                   __hip_bfloat16* __restrict__ hx,
                                                   u32* __restrict__ flags,
                                                   float* __restrict__ out) {
  __shared__ __align__(16) ushort Bf[4][32][64][8];   // 128 KB: Wh slice, B-frag order
  __shared__ __align__(16) float gt[4][4][16][20];    // 20 KB
  __shared__ float obuf[8][16][16];                   // 8 KB out ring (same-thread RW)
  const int tid = threadIdx.x;
  const int l = tid & 63, w = tid >> 6;
  const int jg = blockIdx.x & 63, bg = blockIdx.x >> 6;
  const int j0 = jg * 16, b0 = bg * 16;

  // stage Wh slice into LDS, pre-swizzled to MFMA B-fragment order (once)
  for (int idx = tid; idx < 4 * 32 * 64; idx += 256) {
    int g = idx >> 11, kb = (idx >> 6) & 31, ll = idx & 63;
    const __hip_bfloat16* src =
        whb + ((size_t)(g * H + j0 + (ll & 15))) * H + kb * 32 + (ll >> 4) * 8;
    *reinterpret_cast<uint4*>(&Bf[g][kb][ll][0]) = *reinterpret_cast<const uint4*>(src);
  }
  __syncthreads();

  const int cr = l & 15, kg = l >> 4;
  const int bi = tid >> 4, j = tid & 15;
  const u32* myfl = flags + (size_t)((bg << 6) + w * 16 + (l & 15)) * 16;
  u32* pubfl = flags + (size_t)((bg << 6) + jg) * 16;
  float c = 0.f, h_last = 0.f;

  // gq for t=0 loaded before the loop (no poll at t=0)
  u64 gq_cur = *reinterpret_cast<const u64*>(gx + ((size_t)(b0 + bi) * H + j0 + j) * 4);

  for (int t = 0; t < S; ++t) {
    const __hip_bfloat16* hsrc = hx + (size_t)(t & 1) * (B * H);
    __hip_bfloat16* hdst = hx + (size_t)((t + 1) & 1) * (B * H);

    union { u64 q[2]; short8 s; } ua[8];
    if (t > 0) {
      // flag wait: clean vmcnt window (nothing else outstanding)
      while (!__all(ldw(myfl) >= (u32)t)) ;
      asm volatile("" ::: "memory");

      // h bulk load ONCE (fresh by protocol; these ARE the A-fragments)
      const u64* hp =
          reinterpret_cast<const u64*>(hsrc + (size_t)(b0 + cr) * H + w * 256 + kg * 8);
#pragma unroll
      for (int kk = 0; kk < 8; ++kk) {
        ua[kk].q[0] = ldq(hp + kk * 8);
        ua[kk].q[1] = ldq(hp + kk * 8 + 1);
      }
    } else {
#pragma unroll
      for (int kk = 0; kk < 8; ++kk) { ua[kk].q[0] = 0; ua[kk].q[1] = 0; }
    }

    // gq prefetch for NEXT step: overlaps the h-load RTT, completes well before
    // the drain, consumed next iteration -> never pollutes a poll window
    u64 gq_next;
    {
      int tn = (t < S - 1) ? t + 1 : t;
      gq_next = *reinterpret_cast<const u64*>(
          gx + ((size_t)(tn * B + b0 + bi) * H + j0 + j) * 4);
    }

    // MFMA partials over this wave's K range (B-frags from LDS)
    f32x4 acc[4] = {};
#pragma unroll
    for (int kk = 0; kk < 8; ++kk) {
#pragma unroll
      for (int g = 0; g < 4; ++g) {
        short8 bv = *reinterpret_cast<const short8*>(&Bf[g][w * 8 + kk][l][0]);
        acc[g] = __builtin_amdgcn_mfma_f32_16x16x32_bf16(ua[kk].s, bv, acc[g], 0, 0, 0);
      }
    }
#pragma unroll
    for (int g = 0; g < 4; ++g)
      *reinterpret_cast<f32x4*>(&gt[w][g][cr][kg * 4]) = acc[g];
    bar_lds();   // gt writes visible (lgkm only)

    // cross-wave K reduction + gates (thread owns (batch=bi, hidden=j))
    float sf = 0.f, si = 0.f, so = 0.f, sc = 0.f;
#pragma unroll
    for (int wv = 0; wv < 4; ++wv) {
      sf += gt[wv][0][j][bi];
      si += gt[wv][1][j][bi];
      so += gt[wv][2][j][bi];
      sc += gt[wv][3][j][bi];
    }
    float gf = sf + __uint_as_float((u32)(gq_cur & 0xffffu) << 16);
    float gi = si + __uint_as_float((u32)((gq_cur >> 16) & 0xffffu) << 16);
    float go = so + __uint_as_float((u32)((gq_cur >> 32) & 0xffffu) << 16);
    float gc = sc + __uint_as_float((u32)((gq_cur >> 48) & 0xffffu) << 16);
    gq_cur = gq_next;
    float f = sigm(gf);
    float i_ = sigm(gi);
    float o = sigm(go);
    float cn = f * c + i_ * tanhfast(gc);
    float hn = o * tanhfast(cn);
    c = cn;
    h_last = hn;

    // out -> LDS ring (no global store traffic between flushes)
    obuf[t & 7][bi][j] = hn;

    // flush the ring every 8 steps, right BEFORE the drain (drain absorbs acks)
    if ((t & 7) == 7) {
      int tb = t - 7;
#pragma unroll
      for (int s = 0; s < 8; ++s)
        out[((size_t)((tb + s) * B + b0 + bi)) * H + j0 + j] = obuf[s][bi][j];
    }

    // ---- publish path: pack bf16 h (2 shfl), store, drain, flag ----
    u32 hs16 = (u32)__bfloat16_as_ushort(__float2bfloat16(hn));
    u32 p1 = (hs16 & 0xffffu) | ((u32)__shfl_xor((int)hs16, 1) << 16);
    u32 p2 = (u32)__shfl_xor((int)p1, 2);
    if (t < S - 1) {
      if ((j & 3) == 0) {
        u64 pk = (u64)p1 | ((u64)p2 << 32);
        stq(reinterpret_cast<u64*>(hdst + (size_t)(b0 + bi) * H + j0 + j), pk);
      }
      // drain h (+ any flush) stores, join waves, publish one flag.
      // This s_barrier also serves as the gt WAR barrier for the next step.
      asm volatile("s_waitcnt vmcnt(0)" ::: "memory");
      __builtin_amdgcn_sched_barrier(0);
      __builtin_amdgcn_s_barrier();
      __builtin_amdgcn_sched_barrier(0);
      if (tid == 0) stw(pubfl, (u32)(t + 1));
    }
  }

  // finals (h_S, c_S) — off-protocol, kernel-end drain covers them
  out[(size_t)S * B * H + (size_t)(b0 + bi) * H + j0 + j] = h_last;
  out[(size_t)S * B * H + (size_t)B * H + (size_t)(b0 + bi) * H + j0 + j] = c;
}

extern "C" void kernel_launch(void* const* d_in, const int* in_sizes, int n_in,
                              void* d_out, int out_size, void* d_ws, size_t ws_size,
                              hipStream_t stream) {
  const float* x = (const float*)d_in[0];
  const float* Wx[4] = {(const float*)d_in[1], (const float*)d_in[3],
                        (const float*)d_in[5], (const float*)d_in[7]};
  const float* bx[4] = {(const float*)d_in[2], (const float*)d_in[4],
                        (const float*)d_in[6], (const float*)d_in[8]};
  const float* Wh[4] = {(const float*)d_in[9], (const float*)d_in[11],
                        (const float*)d_in[13], (const float*)d_in[15]};
  const float* bh[4] = {(const float*)d_in[10], (const float*)d_in[12],
                        (const float*)d_in[14], (const float*)d_in[16]};

  char* ws = (char*)d_ws;
  size_t o_flags = 0;                                 // 256 slots x 64B = 16 KB
  size_t o_hx = 16384;
  size_t o_bias = o_hx + (size_t)2 * B * H * 2;       // hx ping-pong bf16: 256 KB
  size_t o_x = o_bias + (size_t)NG * 4;
  size_t o_wx = o_x + (size_t)M * IN * 2;             // xb: 16 MB
  size_t o_wh = o_wx + (size_t)NG * IN * 2;           // wxb: 4 MB
  size_t o_gx = o_wh + (size_t)NG * H * 2;            // whb: 8 MB; gx: 134 MB

  u32* flagsp = (u32*)(ws + o_flags);
  __hip_bfloat16* hxp = (__hip_bfloat16*)(ws + o_hx);
  float* biasp = (float*)(ws + o_bias);
  __hip_bfloat16* xb = (__hip_bfloat16*)(ws + o_x);
  __hip_bfloat16* wxb = (__hip_bfloat16*)(ws + o_wx);
  __hip_bfloat16* whb = (__hip_bfloat16*)(ws + o_wh);
  __hip_bfloat16* gxp = (__hip_bfloat16*)(ws + o_gx);

  // zero only the 16 KB flag array each launch (monotone counters)
  hipMemsetAsync(ws, 0, 16384, stream);

  f2b<<<(M * IN / 4) / 256, 256, 0, stream>>>(x, xb, M * IN / 4);
  {
    int total4 = 4 * (H * IN / 4) + 4 * (H * H / 4);
    wconv<<<(total4 + 255) / 256, 256, 0, stream>>>(
        Wx[0], Wx[1], Wx[2], Wx[3], Wh[0], Wh[1], Wh[2], Wh[3], wxb, whb);
  }
  bias_k<<<NG / 256, 256, 0, stream>>>(bx[0], bx[1], bx[2], bx[3],
                                       bh[0], bh[1], bh[2], bh[3], biasp);

  dim3 gg(NG / 128, M / 128);
  gx_gemm<<<gg, 256, 0, stream>>>(xb, wxb, biasp, gxp);

  lstm_rec<<<256, 256, 0, stream>>>(whb, gxp, hxp, flagsp, (float*)d_out);
}

// Round 14
// 1140.839 us; speedup vs baseline: 1.4436x; 1.0466x over previous
//
#include <hip/hip_runtime.h>
#include <hip/hip_bf16.h>

typedef short short8 __attribute__((ext_vector_type(8)));
typedef float f32x4 __attribute__((ext_vector_type(4)));
typedef unsigned long long u64;
typedef unsigned u32;

constexpr int S = 256, B = 64, IN = 512, H = 1024;
constexpr int M = S * B;        // 16384
constexpr int NG = 4 * H;       // 4096

// ---------------- prep ----------------
__global__ void f2b(const float* __restrict__ s, __hip_bfloat16* __restrict__ d, int n4) {
  int i = blockIdx.x * blockDim.x + threadIdx.x;
  if (i >= n4) return;
  float4 v = reinterpret_cast<const float4*>(s)[i];
  __hip_bfloat16 o[4] = {__float2bfloat16(v.x), __float2bfloat16(v.y),
                         __float2bfloat16(v.z), __float2bfloat16(v.w)};
  *reinterpret_cast<uint2*>(d + 4 * (size_t)i) = *reinterpret_cast<uint2*>(o);
}

// all 8 weight matrices in one launch: Wx 4x(H*IN) then Wh 4x(H*H), float4 units
__global__ void wconv(const float* w0, const float* w1, const float* w2, const float* w3,
                      const float* w4, const float* w5, const float* w6, const float* w7,
                      __hip_bfloat16* __restrict__ wxb, __hip_bfloat16* __restrict__ whb) {
  const int QX = H * IN / 4;
  const int QH = H * H / 4;
  int i = blockIdx.x * blockDim.x + threadIdx.x;
  const float* src;
  __hip_bfloat16* dst;
  int off;
  if (i < 4 * QX) {
    int g = i / QX; off = i - g * QX;
    src = g == 0 ? w0 : g == 1 ? w1 : g == 2 ? w2 : w3;
    dst = wxb + (size_t)g * H * IN;
  } else {
    int k = i - 4 * QX;
    if (k >= 4 * QH) return;
    int g = k / QH; off = k - g * QH;
    src = g == 0 ? w4 : g == 1 ? w5 : g == 2 ? w6 : w7;
    dst = whb + (size_t)g * H * H;
  }
  float4 v = reinterpret_cast<const float4*>(src)[off];
  __hip_bfloat16 o[4] = {__float2bfloat16(v.x), __float2bfloat16(v.y),
                         __float2bfloat16(v.z), __float2bfloat16(v.w)};
  *reinterpret_cast<uint2*>(dst + 4 * (size_t)off) = *reinterpret_cast<uint2*>(o);
}

__global__ void bias_k(const float* bx0, const float* bx1, const float* bx2, const float* bx3,
                       const float* bh0, const float* bh1, const float* bh2, const float* bh3,
                       float* bias) {
  int i = blockIdx.x * blockDim.x + threadIdx.x;
  if (i >= NG) return;
  int g = i >> 10, j = i & 1023;
  const float* bx = g == 0 ? bx0 : g == 1 ? bx1 : g == 2 ? bx2 : bx3;
  const float* bh = g == 0 ? bh0 : g == 1 ? bh1 : g == 2 ? bh2 : bh3;
  bias[i] = bx[j] + bh[j];
}

// ---------------- gx = x @ Wx^T + bias : m97-structure, output [m][j][gate] ----------------
__global__ __launch_bounds__(256) void gx_gemm(const __hip_bfloat16* __restrict__ xb,
                                               const __hip_bfloat16* __restrict__ wxb,
                                               const float* __restrict__ bias,
                                               __hip_bfloat16* __restrict__ gx) {
  __shared__ __align__(16) ushort As[4][128][8];   // 8 KB
  __shared__ __align__(16) ushort Bs[4][128][8];   // 8 KB
  const int tid = threadIdx.x;
  const int l = tid & 63, w = tid >> 6;
  const int m0 = blockIdx.y * 128, n0 = blockIdx.x * 128;
  const int wm = (w >> 1) * 64, wn = (w & 1) * 64;
  const int cr = l & 15, kg = l >> 4;
  f32x4 acc[4][4] = {};

  ushort* Af = &As[0][0][0];
  ushort* Bfl = &Bs[0][0][0];

  for (int k0 = 0; k0 < IN; k0 += 32) {
    __syncthreads();
#pragma unroll
    for (int n = 0; n < 2; ++n) {
      int cA = w * 2 + n;            // chunk 0..7 (1 KB each)
      int f = cA * 64 + l;           // flat 16B-unit index: seg=f>>7, row=f&127
      const __hip_bfloat16* ga = xb + (size_t)(m0 + (f & 127)) * IN + k0 + (f >> 7) * 8;
      const __hip_bfloat16* gb = wxb + (size_t)(n0 + (f & 127)) * IN + k0 + (f >> 7) * 8;
      __builtin_amdgcn_global_load_lds((const u32*)ga, (u32*)(Af + cA * 512), 16, 0, 0);
      __builtin_amdgcn_global_load_lds((const u32*)gb, (u32*)(Bfl + cA * 512), 16, 0, 0);
    }
    __syncthreads();
    short8 a[4], b[4];
#pragma unroll
    for (int mi = 0; mi < 4; ++mi)
      a[mi] = *reinterpret_cast<const short8*>(&As[kg][wm + mi * 16 + cr][0]);
#pragma unroll
    for (int ni = 0; ni < 4; ++ni)
      b[ni] = *reinterpret_cast<const short8*>(&Bs[kg][wn + ni * 16 + cr][0]);
#pragma unroll
    for (int mi = 0; mi < 4; ++mi)
#pragma unroll
      for (int ni = 0; ni < 4; ++ni)
        acc[mi][ni] = __builtin_amdgcn_mfma_f32_16x16x32_bf16(a[mi], b[ni], acc[mi][ni], 0, 0, 0);
  }

#pragma unroll
  for (int ni = 0; ni < 4; ++ni) {
    int n = n0 + wn + ni * 16 + cr;
    float bv = bias[n];
    int g = n >> 10, j = n & 1023;
#pragma unroll
    for (int mi = 0; mi < 4; ++mi) {
#pragma unroll
      for (int r = 0; r < 4; ++r) {
        int m = m0 + wm + mi * 16 + kg * 4 + r;
        gx[((size_t)m * H + j) * 4 + g] = __float2bfloat16(acc[mi][ni][r] + bv);
      }
    }
  }
}

__device__ __forceinline__ u64 ldq(const u64* p) {
  return __hip_atomic_load(p, __ATOMIC_RELAXED, __HIP_MEMORY_SCOPE_AGENT);
}
__device__ __forceinline__ u32 ldw(const u32* p) {
  return __hip_atomic_load(p, __ATOMIC_RELAXED, __HIP_MEMORY_SCOPE_AGENT);
}
__device__ __forceinline__ void stw(u32* p, u32 v) {
  __hip_atomic_store(p, v, __ATOMIC_RELAXED, __HIP_MEMORY_SCOPE_AGENT);
}
__device__ __forceinline__ void stq(u64* p, u64 v) {
  __hip_atomic_store(p, v, __ATOMIC_RELAXED, __HIP_MEMORY_SCOPE_AGENT);
}
__device__ __forceinline__ float sigm(float x) {
  return __builtin_amdgcn_rcpf(1.f + __expf(-x));
}
__device__ __forceinline__ float tanhfast(float x) {
  return 2.f * __builtin_amdgcn_rcpf(1.f + __expf(-2.f * x)) - 1.f;
}
// block barrier that only drains LDS (no vmcnt -> no store-ack RTT)
__device__ __forceinline__ void bar_lds() {
  asm volatile("s_waitcnt lgkmcnt(0)" ::: "memory");
  __builtin_amdgcn_sched_barrier(0);
  __builtin_amdgcn_s_barrier();
  __builtin_amdgcn_sched_barrier(0);
}

// ---------------- persistent recurrence: per-wave drain -> per-wave flag ----------------
// r10/r13 protocol with the producer-side block barrier REMOVED from the flag
// path: each wave drains its own 16 h-stores (per-wave vmcnt) and its lane 0
// publishes a per-(block,wave) flag immediately. Consumer lane l polls slot
// (producer jg' = w*16+(l&15), wave l>>4) -> 64 lanes = exactly the 64
// (producer,wave) pairs whose rows it loads. The gt WAR barrier moves after
// the publish (off the inter-block critical path).
__global__ __launch_bounds__(256, 1) void lstm_rec(const __hip_bfloat16* __restrict__ whb,
                                                   const __hip_bfloat16* __restrict__ gx,
                                                   __hip_bfloat16* __restrict__ hx,
                                                   u32* __restrict__ flags,
                                                   float* __restrict__ out) {
  __shared__ __align__(16) ushort Bf[4][32][64][8];   // 128 KB: Wh slice, B-frag order
  __shared__ __align__(16) float gt[4][4][16][20];    // 20 KB
  __shared__ float obuf[8][16][16];                   // 8 KB out ring (same-thread RW)
  const int tid = threadIdx.x;
  const int l = tid & 63, w = tid >> 6;
  const int jg = blockIdx.x & 63, bg = blockIdx.x >> 6;
  const int j0 = jg * 16, b0 = bg * 16;

  // stage Wh slice into LDS, pre-swizzled to MFMA B-fragment order (once)
  for (int idx = tid; idx < 4 * 32 * 64; idx += 256) {
    int g = idx >> 11, kb = (idx >> 6) & 31, ll = idx & 63;
    const __hip_bfloat16* src =
        whb + ((size_t)(g * H + j0 + (ll & 15))) * H + kb * 32 + (ll >> 4) * 8;
    *reinterpret_cast<uint4*>(&Bf[g][kb][ll][0]) = *reinterpret_cast<const uint4*>(src);
  }
  __syncthreads();

  const int cr = l & 15, kg = l >> 4;
  const int bi = tid >> 4, j = tid & 15;
  // consumer: poll (producer block jg'=w*16+(l&15), wave l>>4) of own bg
  const u32* myfl =
      flags + ((size_t)(((bg << 6) + w * 16 + (l & 15)) << 2) + (l >> 4)) * 16;
  // producer: this block's wave-w flag slot
  u32* pubfl = flags + ((size_t)((((bg << 6) + jg) << 2) + w)) * 16;
  float c = 0.f, h_last = 0.f;

  // gq for t=0 loaded before the loop (no poll at t=0)
  u64 gq_cur = *reinterpret_cast<const u64*>(gx + ((size_t)(b0 + bi) * H + j0 + j) * 4);

  for (int t = 0; t < S; ++t) {
    const __hip_bfloat16* hsrc = hx + (size_t)(t & 1) * (B * H);
    __hip_bfloat16* hdst = hx + (size_t)((t + 1) & 1) * (B * H);

    union { u64 q[2]; short8 s; } ua[8];
    if (t > 0) {
      // flag wait: 64 lanes cover the 64 (producer,wave) dependencies
      while (!__all(ldw(myfl) >= (u32)t)) ;
      asm volatile("" ::: "memory");

      // h bulk load ONCE (fresh by protocol; these ARE the A-fragments)
      const u64* hp =
          reinterpret_cast<const u64*>(hsrc + (size_t)(b0 + cr) * H + w * 256 + kg * 8);
#pragma unroll
      for (int kk = 0; kk < 8; ++kk) {
        ua[kk].q[0] = ldq(hp + kk * 8);
        ua[kk].q[1] = ldq(hp + kk * 8 + 1);
      }
    } else {
#pragma unroll
      for (int kk = 0; kk < 8; ++kk) { ua[kk].q[0] = 0; ua[kk].q[1] = 0; }
    }

    // gq prefetch for NEXT step (overlaps h-load RTT; consumed next iteration)
    u64 gq_next;
    {
      int tn = (t < S - 1) ? t + 1 : t;
      gq_next = *reinterpret_cast<const u64*>(
          gx + ((size_t)(tn * B + b0 + bi) * H + j0 + j) * 4);
    }

    // MFMA partials over this wave's K range (B-frags from LDS)
    f32x4 acc[4] = {};
#pragma unroll
    for (int kk = 0; kk < 8; ++kk) {
#pragma unroll
      for (int g = 0; g < 4; ++g) {
        short8 bv = *reinterpret_cast<const short8*>(&Bf[g][w * 8 + kk][l][0]);
        acc[g] = __builtin_amdgcn_mfma_f32_16x16x32_bf16(ua[kk].s, bv, acc[g], 0, 0, 0);
      }
    }
#pragma unroll
    for (int g = 0; g < 4; ++g)
      *reinterpret_cast<f32x4*>(&gt[w][g][cr][kg * 4]) = acc[g];
    bar_lds();   // gt writes visible (lgkm only)

    // cross-wave K reduction + gates (thread owns (batch=bi, hidden=j))
    float sf = 0.f, si = 0.f, so = 0.f, sc = 0.f;
#pragma unroll
    for (int wv = 0; wv < 4; ++wv) {
      sf += gt[wv][0][j][bi];
      si += gt[wv][1][j][bi];
      so += gt[wv][2][j][bi];
      sc += gt[wv][3][j][bi];
    }
    float gf = sf + __uint_as_float((u32)(gq_cur & 0xffffu) << 16);
    float gi = si + __uint_as_float((u32)((gq_cur >> 16) & 0xffffu) << 16);
    float go = so + __uint_as_float((u32)((gq_cur >> 32) & 0xffffu) << 16);
    float gc = sc + __uint_as_float((u32)((gq_cur >> 48) & 0xffffu) << 16);
    gq_cur = gq_next;
    float f = sigm(gf);
    float i_ = sigm(gi);
    float o = sigm(go);
    float cn = f * c + i_ * tanhfast(gc);
    float hn = o * tanhfast(cn);
    c = cn;
    h_last = hn;

    // ---- publish path: pack bf16 h (2 shfl), store, per-wave drain, per-wave flag ----
    u32 hs16 = (u32)__bfloat16_as_ushort(__float2bfloat16(hn));
    u32 p1 = (hs16 & 0xffffu) | ((u32)__shfl_xor((int)hs16, 1) << 16);
    u32 p2 = (u32)__shfl_xor((int)p1, 2);
    if (t < S - 1) {
      if ((j & 3) == 0) {
        u64 pk = (u64)p1 | ((u64)p2 << 32);
        stq(reinterpret_cast<u64*>(hdst + (size_t)(b0 + bi) * H + j0 + j), pk);
      }
      // drain THIS WAVE's h stores only, then its lane 0 publishes immediately
      asm volatile("s_waitcnt vmcnt(0)" ::: "memory");
      __builtin_amdgcn_sched_barrier(0);
      if (l == 0) stw(pubfl, (u32)(t + 1));
    }

    // out -> LDS ring; flush every 8 steps (after the flag: off the hot path)
    obuf[t & 7][bi][j] = hn;
    if ((t & 7) == 7) {
      int tb = t - 7;
#pragma unroll
      for (int s = 0; s < 8; ++s)
        out[((size_t)((tb + s) * B + b0 + bi)) * H + j0 + j] = obuf[s][bi][j];
    }

    bar_lds();   // gt WAR for next step (after publish -> off inter-block path)
  }

  // finals (h_S, c_S) — off-protocol, kernel-end drain covers them
  out[(size_t)S * B * H + (size_t)(b0 + bi) * H + j0 + j] = h_last;
  out[(size_t)S * B * H + (size_t)B * H + (size_t)(b0 + bi) * H + j0 + j] = c;
}

extern "C" void kernel_launch(void* const* d_in, const int* in_sizes, int n_in,
                              void* d_out, int out_size, void* d_ws, size_t ws_size,
                              hipStream_t stream) {
  const float* x = (const float*)d_in[0];
  const float* Wx[4] = {(const float*)d_in[1], (const float*)d_in[3],
                        (const float*)d_in[5], (const float*)d_in[7]};
  const float* bx[4] = {(const float*)d_in[2], (const float*)d_in[4],
                        (const float*)d_in[6], (const float*)d_in[8]};
  const float* Wh[4] = {(const float*)d_in[9], (const float*)d_in[11],
                        (const float*)d_in[13], (const float*)d_in[15]};
  const float* bh[4] = {(const float*)d_in[10], (const float*)d_in[12],
                        (const float*)d_in[14], (const float*)d_in[16]};

  char* ws = (char*)d_ws;
  size_t o_flags = 0;                                 // 1024 slots x 64B = 64 KB
  size_t o_hx = 65536;
  size_t o_bias = o_hx + (size_t)2 * B * H * 2;       // hx ping-pong bf16: 256 KB
  size_t o_x = o_bias + (size_t)NG * 4;
  size_t o_wx = o_x + (size_t)M * IN * 2;             // xb: 16 MB
  size_t o_wh = o_wx + (size_t)NG * IN * 2;           // wxb: 4 MB
  size_t o_gx = o_wh + (size_t)NG * H * 2;            // whb: 8 MB; gx: 134 MB

  u32* flagsp = (u32*)(ws + o_flags);
  __hip_bfloat16* hxp = (__hip_bfloat16*)(ws + o_hx);
  float* biasp = (float*)(ws + o_bias);
  __hip_bfloat16* xb = (__hip_bfloat16*)(ws + o_x);
  __hip_bfloat16* wxb = (__hip_bfloat16*)(ws + o_wx);
  __hip_bfloat16* whb = (__hip_bfloat16*)(ws + o_wh);
  __hip_bfloat16* gxp = (__hip_bfloat16*)(ws + o_gx);

  // zero the 64 KB flag array each launch (monotone counters)
  hipMemsetAsync(ws, 0, 65536, stream);

  f2b<<<(M * IN / 4) / 256, 256, 0, stream>>>(x, xb, M * IN / 4);
  {
    int total4 = 4 * (H * IN / 4) + 4 * (H * H / 4);
    wconv<<<(total4 + 255) / 256, 256, 0, stream>>>(
        Wx[0], Wx[1], Wx[2], Wx[3], Wh[0], Wh[1], Wh[2], Wh[3], wxb, whb);
  }
  bias_k<<<NG / 256, 256, 0, stream>>>(bx[0], bx[1], bx[2], bx[3],
                                       bh[0], bh[1], bh[2], bh[3], biasp);

  dim3 gg(NG / 128, M / 128);
  gx_gemm<<<gg, 256, 0, stream>>>(xb, wxb, biasp, gxp);

  lstm_rec<<<256, 256, 0, stream>>>(whb, gxp, hxp, flagsp, (float*)d_out);
}